// Round 5
// baseline (1784.509 us; speedup 1.0000x reference)
//
#include <hip/hip_runtime.h>
#include <hip/hip_bf16.h>

// Problem constants (from reference). All I/O is float32 (verified R2).
constexpr int T  = 6;
constexpr int S  = 66;    // 3*J
constexpr int IN = 256;
constexpr int H  = 8;
constexpr int D  = 32;
constexpr int J  = 22;
constexpr float NEG = -9e15f;
constexpr float INV_SQRT_D = 0.17677669529663688110f; // 1/sqrt(32)

// ---------------- LDS map (bytes), SMEM 54,048; 3 blocks/CU (162,144<=163,840) ----
// proj stage (per 64-K chunk, x4):   xh/xl[80][72]sh @0/11,520; wh/wl[96][72]sh @23,040/36,864 (end 50,688)
// attn persistent (after proj):
//   qh/ql bf16[80][36] @ 0 / 5,760      (stride 72 B; b64 frag reads, 16-lane distinct banks)
//   kh/kl bf16[80][36] @ 11,520/17,280  (end 23,040)
//   sc f32[66][66]     @ 23,040         (end 40,464)
//   vTh/vTl bf16[32][104] @ 40,464/47,120 (stride 208 B, b128-aligned; end 53,776)
//   inv f32[66]        @ 53,776         (end 54,040)
// softmax->PV overlays (q/k/sc-front dead, read-then-barrier protected):
//   Ph/Pl bf16[66][104] @ 0 / 13,728    (end 27,456; garbage-row overreads OK)
//   aoT   bf16[32][104] @ 27,456        (end 34,112; overlays dead sc)
// phase-6 overlays (vT dead after PV):
//   Wch/Wcl bf16[32][104] @ 34,112/40,768 (end 47,424)
#define XH_OFF   0
#define XL_OFF   11520
#define WH_OFF   23040
#define WL_OFF   36864
#define QH_OFF   0
#define QL_OFF   5760
#define KH_OFF   11520
#define KL_OFF   17280
#define SC_OFF   23040
#define VTH_OFF  40464
#define VTL_OFF  47120
#define INV_OFF  53776
#define PH_OFF   0
#define PL_OFF   13728
#define AOT_OFF  27456
#define WCH_OFF  34112
#define WCL_OFF  40768
#define SMEM_BYTES 54048

typedef float f32x4  __attribute__((ext_vector_type(4)));
typedef short bf16x8 __attribute__((ext_vector_type(8)));
typedef short s4v    __attribute__((ext_vector_type(4)));

__device__ __forceinline__ unsigned short rne16(float f) {
    unsigned u = __float_as_uint(f);
    return (unsigned short)((u + 0x7FFFu + ((u >> 16) & 1u)) >> 16);
}
__device__ __forceinline__ float bfh2f(unsigned short h) {
    return __uint_as_float(((unsigned)h) << 16);
}
// split two f32 into packed bf16 hi (rne) and bf16 lo (rne of residual)
__device__ __forceinline__ void split2(float a, float b, unsigned& hi, unsigned& lo) {
    unsigned short ha = rne16(a), hb = rne16(b);
    hi = (unsigned)ha | ((unsigned)hb << 16);
    unsigned short la = rne16(a - bfh2f(ha)), lb = rne16(b - bfh2f(hb));
    lo = (unsigned)la | ((unsigned)lb << 16);
}
// load 8 bf16 from an 8-byte-aligned LDS address as two b64 reads
__device__ __forceinline__ bf16x8 ld_bf16x8_a8(const short* p) {
    s4v a = *(const s4v*)p;
    s4v b = *(const s4v*)(p + 4);
    return __builtin_shufflevector(a, b, 0, 1, 2, 3, 4, 5, 6, 7);
}

__global__ __launch_bounds__(256, 3)
void mha_fused_kernel(const float* __restrict__ x,
                      const float* __restrict__ Wq, const float* __restrict__ bq,
                      const float* __restrict__ Wk, const float* __restrict__ bk,
                      const float* __restrict__ Wv, const float* __restrict__ bv,
                      const float* __restrict__ Wc, const float* __restrict__ bc,
                      float* __restrict__ out)
{
    __shared__ __align__(16) unsigned char smem[SMEM_BYTES];

    const int tid = threadIdx.x;
    const int bth = blockIdx.x;          // [0, 512*6*8)
    const int h   = bth & 7;
    const int bt  = bth >> 3;            // b*T + t

    const int wid  = tid >> 6;           // wave 0..3
    const int lane = tid & 63;
    const int l15  = lane & 15;
    const int quad = lane >> 4;

    // ---------------- Phase 1: q,k,v projections via split-bf16 MFMA (as R4) ---------
    f32x4 accs[8];
    #pragma unroll
    for (int jj = 0; jj < 8; ++jj) accs[jj] = (f32x4){0.f, 0.f, 0.f, 0.f};

    for (int chunk = 0; chunk < 4; ++chunk) {    // K = 4 x 64
        __syncthreads();
        {   // x tile: 66 x 64 f32 -> hi/lo bf16
            const float* xg = x + (size_t)bt * S * IN + chunk * 64;
            for (int u = tid; u < 1056; u += 256) {
                int s = u >> 4, c = u & 15;
                float4 v = *(const float4*)(xg + (size_t)s * IN + c * 4);
                uint2 hi, lo;
                split2(v.x, v.y, hi.x, lo.x);
                split2(v.z, v.w, hi.y, lo.y);
                ((uint2*)(smem + XH_OFF + s * 144))[c] = hi;
                ((uint2*)(smem + XL_OFF + s * 144))[c] = lo;
            }
        }
        for (int u = tid; u < 1536; u += 256) {   // W slices: 96 x 64
            int row = u >> 4, c = u & 15;
            int m = row >> 5, dd = row & 31;
            const float* Wm = (m == 0) ? Wq : (m == 1) ? Wk : Wv;
            float4 v = *(const float4*)(Wm + (size_t)(h * 32 + dd) * IN + chunk * 64 + c * 4);
            uint2 hi, lo;
            split2(v.x, v.y, hi.x, lo.x);
            split2(v.z, v.w, hi.y, lo.y);
            ((uint2*)(smem + WH_OFF + row * 144))[c] = hi;
            ((uint2*)(smem + WL_OFF + row * 144))[c] = lo;
        }
        __syncthreads();

        const short* xh = (const short*)(smem + XH_OFF);
        const short* xl = (const short*)(smem + XL_OFF);
        const short* wh = (const short*)(smem + WH_OFF);
        const short* wl = (const short*)(smem + WL_OFF);

        for (int jj = 0; jj < 8; ++jj) {
            int j = wid + 4 * jj;
            if (j >= 30) break;                      // wave-uniform
            int mat = j / 10, rr = j - mat * 10;
            int mtile = rr >> 1, ntile = rr & 1;
            int arow = (mtile * 16 + l15) * 72 + quad * 8;
            int brow = (mat * 32 + ntile * 16 + l15) * 72 + quad * 8;
            #pragma unroll
            for (int kk = 0; kk < 2; ++kk) {
                bf16x8 ah = *(const bf16x8*)(xh + arow + kk * 32);
                bf16x8 al = *(const bf16x8*)(xl + arow + kk * 32);
                bf16x8 bh = *(const bf16x8*)(wh + brow + kk * 32);
                bf16x8 bl = *(const bf16x8*)(wl + brow + kk * 32);
                accs[jj] = __builtin_amdgcn_mfma_f32_16x16x32_bf16(ah, bh, accs[jj], 0, 0, 0);
                accs[jj] = __builtin_amdgcn_mfma_f32_16x16x32_bf16(ah, bl, accs[jj], 0, 0, 0);
                accs[jj] = __builtin_amdgcn_mfma_f32_16x16x32_bf16(al, bh, accs[jj], 0, 0, 0);
            }
        }
    }
    __syncthreads();   // stage dead; epilogue overwrites it

    // ---------------- Epilogue: q/k -> hi/lo [s][d]; v -> relu, hi/lo transposed [d][s]
    {
        short* qh = (short*)(smem + QH_OFF); short* ql = (short*)(smem + QL_OFF);
        short* kh = (short*)(smem + KH_OFF); short* kl = (short*)(smem + KL_OFF);
        for (int jj = 0; jj < 8; ++jj) {
            int j = wid + 4 * jj;
            if (j >= 30) break;
            int mat = j / 10, rr = j - mat * 10;
            int mtile = rr >> 1, ntile = rr & 1;
            int dd = ntile * 16 + l15;
            const float* bias_p = (mat == 0) ? bq : (mat == 1) ? bk : bv;
            float bias = bias_p[h * 32 + dd];
            if (mat < 2) {
                short* bh = (mat == 0) ? qh : kh;
                short* bl = (mat == 0) ? ql : kl;
                #pragma unroll
                for (int reg = 0; reg < 4; ++reg) {
                    int s = mtile * 16 + quad * 4 + reg;
                    if (s < 66) {
                        float v = accs[jj][reg] + bias;
                        unsigned short hi = rne16(v);
                        unsigned short lo = rne16(v - bfh2f(hi));
                        bh[s * 36 + dd] = (short)hi;
                        bl[s * 36 + dd] = (short)lo;
                    }
                }
            } else {
                int sbase = mtile * 16 + quad * 4;
                unsigned short hv[4], lv[4];
                #pragma unroll
                for (int reg = 0; reg < 4; ++reg) {
                    int s = sbase + reg;
                    float v = (s < 66) ? fmaxf(accs[jj][reg] + bias, 0.f) : 0.f; // zero K-pad
                    hv[reg] = rne16(v);
                    lv[reg] = rne16(v - bfh2f(hv[reg]));
                }
                uint2 ph, pl;
                ph.x = (unsigned)hv[0] | ((unsigned)hv[1] << 16);
                ph.y = (unsigned)hv[2] | ((unsigned)hv[3] << 16);
                pl.x = (unsigned)lv[0] | ((unsigned)lv[1] << 16);
                pl.y = (unsigned)lv[2] | ((unsigned)lv[3] << 16);
                *(uint2*)(smem + VTH_OFF + dd * 208 + 2 * sbase) = ph;
                *(uint2*)(smem + VTL_OFF + dd * 208 + 2 * sbase) = pl;
            }
        }
        // zero vT cols 80..103 (beyond epilogue coverage; K-pad safety for PV)
        for (int u = tid; u < 768; u += 256) {
            int comp = u >= 384 ? 1 : 0, rem = comp ? u - 384 : u;
            int row = rem / 12, kcol = 80 + 2 * (rem % 12);
            *(unsigned*)(smem + (comp ? VTL_OFF : VTH_OFF) + row * 208 + 2 * kcol) = 0u;
        }
    }
    __syncthreads();

    // ---------------- Phase 3: sc = mask * (q k^T) / sqrt(D) via split MFMA ----------
    {
        const short* qh = (const short*)(smem + QH_OFF);
        const short* ql = (const short*)(smem + QL_OFF);
        const short* kh = (const short*)(smem + KH_OFF);
        const short* kl = (const short*)(smem + KL_OFF);
        float* sc = (float*)(smem + SC_OFF);
        for (int t = 0; t < 7; ++t) {
            int tt = wid + 4 * t;
            if (tt >= 25) break;                 // wave-uniform
            int mq = tt / 5, mk = tt - mq * 5;
            int aoff = (mq * 16 + l15) * 36 + quad * 8;
            int boff = (mk * 16 + l15) * 36 + quad * 8;
            bf16x8 ah = ld_bf16x8_a8(qh + aoff);
            bf16x8 al = ld_bf16x8_a8(ql + aoff);
            bf16x8 bh = ld_bf16x8_a8(kh + boff);
            bf16x8 bl = ld_bf16x8_a8(kl + boff);
            f32x4 acc = (f32x4){0.f, 0.f, 0.f, 0.f};
            acc = __builtin_amdgcn_mfma_f32_16x16x32_bf16(ah, bh, acc, 0, 0, 0);
            acc = __builtin_amdgcn_mfma_f32_16x16x32_bf16(ah, bl, acc, 0, 0, 0);
            acc = __builtin_amdgcn_mfma_f32_16x16x32_bf16(al, bh, acc, 0, 0, 0);
            int ks = mk * 16 + l15;
            #pragma unroll
            for (int reg = 0; reg < 4; ++reg) {
                int qs = mq * 16 + quad * 4 + reg;
                if (qs < 66 && ks < 66) {
                    bool masked = (qs < J && ks >= 2 * J) || (qs >= 2 * J && ks < J);
                    sc[qs * 66 + ks] = masked ? 0.f : acc[reg] * INV_SQRT_D;
                }
            }
        }
    }
    __syncthreads();

    // ---------------- Phase 4: prune + softmax (16-lane groups, regs + shuffles) ------
    // Writes UNNORMALIZED e as hi/lo bf16 P (1/sum folded into PV); zero K-pad cols.
    {
        const float* sc = (const float*)(smem + SC_OFF);
        const int group = tid >> 4, lane16 = tid & 15;
        float val[5][5];
        #pragma unroll
        for (int i = 0; i < 5; ++i) {
            int r = group + 16 * i;
            #pragma unroll
            for (int tt = 0; tt < 5; ++tt) {
                int c = lane16 + 16 * tt;
                val[i][tt] = (r < 66 && c < 66) ? sc[r * 66 + c] : -INFINITY;
            }
        }
        __syncthreads();   // all sc reads done -> P may overlay sc front

        short* Ph = (short*)(smem + PH_OFF);
        short* Pl = (short*)(smem + PL_OFF);
        float* inv = (float*)(smem + INV_OFF);
        #pragma unroll
        for (int i = 0; i < 5; ++i) {
            int r = group + 16 * i;
            if (r >= 66) continue;               // group-uniform
            float m = -INFINITY;
            #pragma unroll
            for (int tt = 0; tt < 5; ++tt) m = fmaxf(m, val[i][tt]);
            m = fmaxf(m, __shfl_xor(m, 1));
            m = fmaxf(m, __shfl_xor(m, 2));
            m = fmaxf(m, __shfl_xor(m, 4));
            m = fmaxf(m, __shfl_xor(m, 8));
            const float thr = m / 9.0f;
            float e[5], lsum = 0.f, rmax = -INFINITY;
            #pragma unroll
            for (int tt = 0; tt < 5; ++tt) {
                float sv = val[i][tt];
                float pr = (fabsf(sv) <= thr) ? NEG : sv;   // -INF sentinels stay below
                val[i][tt] = pr;
                rmax = fmaxf(rmax, pr);
            }
            rmax = fmaxf(rmax, __shfl_xor(rmax, 1));
            rmax = fmaxf(rmax, __shfl_xor(rmax, 2));
            rmax = fmaxf(rmax, __shfl_xor(rmax, 4));
            rmax = fmaxf(rmax, __shfl_xor(rmax, 8));
            #pragma unroll
            for (int tt = 0; tt < 5; ++tt) {
                int c = lane16 + 16 * tt;
                float ev = (c < 66) ? __expf(val[i][tt] - rmax) : 0.f;
                e[tt] = ev;
                lsum += ev;
            }
            lsum += __shfl_xor(lsum, 1);
            lsum += __shfl_xor(lsum, 2);
            lsum += __shfl_xor(lsum, 4);
            lsum += __shfl_xor(lsum, 8);
            #pragma unroll
            for (int tt = 0; tt < 6; ++tt) {     // cols 0..95: data or zero pad
                int c = lane16 + 16 * tt;
                if (c >= 104) continue;
                unsigned short hi = 0, lo = 0;
                if (c < 66) {
                    float ev = e[tt];
                    hi = rne16(ev);
                    lo = rne16(ev - bfh2f(hi));
                }
                if (c < 96) {
                    Ph[r * 104 + c] = (short)hi;
                    Pl[r * 104 + c] = (short)lo;
                }
            }
            if (lane16 == 0) inv[r] = 1.0f / lsum;
        }
    }
    __syncthreads();

    // ---------------- Phase 5: aoT = (P @ v)^T * inv, bf16-hi, via MFMA --------------
    {
        const short* Ph = (const short*)(smem + PH_OFF);
        const short* Pl = (const short*)(smem + PL_OFF);
        const short* vh = (const short*)(smem + VTH_OFF);
        const short* vl = (const short*)(smem + VTL_OFF);
        const float* inv = (const float*)(smem + INV_OFF);
        for (int t = 0; t < 3; ++t) {
            int tt = wid + 4 * t;
            if (tt >= 10) break;
            int mq = tt >> 1, nd = tt & 1;
            f32x4 acc = (f32x4){0.f, 0.f, 0.f, 0.f};
            #pragma unroll
            for (int ks = 0; ks < 3; ++ks) {
                const short* ap = Ph + (mq * 16 + l15) * 104 + ks * 32 + quad * 8;
                const short* alp = Pl + (mq * 16 + l15) * 104 + ks * 32 + quad * 8;
                const short* bp = vh + (nd * 16 + l15) * 104 + ks * 32 + quad * 8;
                const short* blp = vl + (nd * 16 + l15) * 104 + ks * 32 + quad * 8;
                bf16x8 a = *(const bf16x8*)ap;
                bf16x8 al8 = *(const bf16x8*)alp;
                bf16x8 b = *(const bf16x8*)bp;
                bf16x8 bl8 = *(const bf16x8*)blp;
                acc = __builtin_amdgcn_mfma_f32_16x16x32_bf16(a, b, acc, 0, 0, 0);
                acc = __builtin_amdgcn_mfma_f32_16x16x32_bf16(al8, b, acc, 0, 0, 0);
                acc = __builtin_amdgcn_mfma_f32_16x16x32_bf16(a, bl8, acc, 0, 0, 0);
            }
            int dd = nd * 16 + l15, sbase = mq * 16 + quad * 4;
            unsigned short hv[4];
            #pragma unroll
            for (int reg = 0; reg < 4; ++reg) {
                int qs = sbase + reg;
                float o = (qs < 66) ? acc[reg] * inv[qs] : 0.f;   // zero K-pad
                hv[reg] = rne16(o);
            }
            uint2 pk;
            pk.x = (unsigned)hv[0] | ((unsigned)hv[1] << 16);
            pk.y = (unsigned)hv[2] | ((unsigned)hv[3] << 16);
            *(uint2*)(smem + AOT_OFF + dd * 208 + 2 * sbase) = pk;
        }
        // zero aoT cols 80..103
        for (int u = tid; u < 384; u += 256) {
            int row = u / 12, kcol = 80 + 2 * (u % 12);
            *(unsigned*)(smem + AOT_OFF + row * 208 + 2 * kcol) = 0u;
        }
    }
    __syncthreads();

    // ---------------- Stage Wc hi/lo (overlays dead sc/vT) ---------------------------
    {
        for (int u = tid; u < 726; u += 256) {           // 22 rows x 33 float2
            int row = u / 33, cp = u - row * 33;
            float2 w = *(const float2*)(Wc + row * 66 + 2 * cp);
            unsigned hi, lo;
            split2(w.x, w.y, hi, lo);
            *(unsigned*)(smem + WCH_OFF + row * 208 + 4 * cp) = hi;
            *(unsigned*)(smem + WCL_OFF + row * 208 + 4 * cp) = lo;
        }
        for (int u = tid; u < 836; u += 256) {           // zero cols 66..103, rows 0..21
            int comp = u >= 418 ? 1 : 0, rem = comp ? u - 418 : u;
            int row = rem / 19, kcol = 66 + 2 * (rem % 19);
            *(unsigned*)(smem + (comp ? WCL_OFF : WCH_OFF) + row * 208 + 2 * kcol) = 0u;
        }
    }
    __syncthreads();

    // ---------------- Phase 6: out = Wc @ ao + bc via MFMA ---------------------------
    {
        const short* Wch = (const short*)(smem + WCH_OFF);
        const short* Wcl = (const short*)(smem + WCL_OFF);
        const short* aoT = (const short*)(smem + AOT_OFF);
        int mj = wid >> 1, nd = wid & 1;
        f32x4 acc = (f32x4){0.f, 0.f, 0.f, 0.f};
        #pragma unroll
        for (int ks = 0; ks < 3; ++ks) {
            bf16x8 a  = *(const bf16x8*)(Wch + (mj * 16 + l15) * 104 + ks * 32 + quad * 8);
            bf16x8 al8 = *(const bf16x8*)(Wcl + (mj * 16 + l15) * 104 + ks * 32 + quad * 8);
            bf16x8 b  = *(const bf16x8*)(aoT + (nd * 16 + l15) * 104 + ks * 32 + quad * 8);
            acc = __builtin_amdgcn_mfma_f32_16x16x32_bf16(a, b, acc, 0, 0, 0);
            acc = __builtin_amdgcn_mfma_f32_16x16x32_bf16(al8, b, acc, 0, 0, 0);
        }
        int dd = nd * 16 + l15;
        #pragma unroll
        for (int reg = 0; reg < 4; ++reg) {
            int j = mj * 16 + quad * 4 + reg;
            if (j < 22) {
                size_t o = (size_t)(bt * J + j) * (H * D) + h * 32 + dd;
                out[o] = acc[reg] + bc[j];
            }
        }
    }
}

extern "C" void kernel_launch(void* const* d_in, const int* in_sizes, int n_in,
                              void* d_out, int out_size, void* d_ws, size_t ws_size,
                              hipStream_t stream) {
    const float* x  = (const float*)d_in[0];
    const float* Wq = (const float*)d_in[1];
    const float* bq = (const float*)d_in[2];
    const float* Wk = (const float*)d_in[3];
    const float* bk = (const float*)d_in[4];
    const float* Wv = (const float*)d_in[5];
    const float* bv = (const float*)d_in[6];
    const float* Wc = (const float*)d_in[7];
    const float* bc = (const float*)d_in[8];
    float* out = (float*)d_out;

    const int B = 512;
    dim3 grid(B * T * H), block(256);
    hipLaunchKernelGGL(mha_fused_kernel, grid, block, 0, stream,
                       x, Wq, bq, Wk, bk, Wv, bv, Wc, bc, out);
}

// Round 6
// 1359.168 us; speedup vs baseline: 1.3129x; 1.3129x over previous
//
#include <hip/hip_runtime.h>
#include <hip/hip_bf16.h>

// Problem constants (from reference). All I/O is float32 (verified R2).
constexpr int T  = 6;
constexpr int S  = 66;    // 3*J
constexpr int IN = 256;
constexpr int H  = 8;
constexpr int D  = 32;
constexpr int J  = 22;
constexpr float NEG = -9e15f;
constexpr float INV_SQRT_D = 0.17677669529663688110f; // 1/sqrt(32)

// ---------------- LDS map (bytes), SMEM 53,016 -> LDS_Block_Size 53,248 (52 KiB) ----
// 3 blocks/CU PROVEN at 53,248 (R2/R4); 54,272 drops to 2 blocks/CU (R5 post-mortem).
// proj stage (per 64-K chunk, x4): xh/xl[80][72]sh @0/11,520; wh/wl[96][72]sh @23,040/36,864 (end 50,688)
// attn persistent (after proj):
//   qh/ql bf16[80][36] @ 0 / 5,760      kh/kl @ 11,520/17,280 (end 23,040)
//   sc f32[66][66]     @ 23,040         (end 40,464)
//   vTh/vTl bf16[32][96] @ 40,464/46,608 (stride 192 B, 16B-aligned rows; end 52,752)
//   inv f32[66]        @ 52,752         (end 53,016)
// softmax->PV overlays: Ph/Pl bf16[66][104] @ 0/13,728 (end 27,456); aoT bf16[32][104] @ 27,456 (end 34,112)
// phase-6 overlays (vT dead): Wch/Wcl bf16[32][104] @ 34,112/40,768 (end 47,424)
#define XH_OFF   0
#define XL_OFF   11520
#define WH_OFF   23040
#define WL_OFF   36864
#define QH_OFF   0
#define QL_OFF   5760
#define KH_OFF   11520
#define KL_OFF   17280
#define SC_OFF   23040
#define VTH_OFF  40464
#define VTL_OFF  46608
#define INV_OFF  52752
#define PH_OFF   0
#define PL_OFF   13728
#define AOT_OFF  27456
#define WCH_OFF  34112
#define WCL_OFF  40768
#define SMEM_BYTES 53016

typedef float f32x4  __attribute__((ext_vector_type(4)));
typedef short bf16x8 __attribute__((ext_vector_type(8)));
typedef short s4v    __attribute__((ext_vector_type(4)));

__device__ __forceinline__ unsigned short rne16(float f) {
    unsigned u = __float_as_uint(f);
    return (unsigned short)((u + 0x7FFFu + ((u >> 16) & 1u)) >> 16);
}
__device__ __forceinline__ float bfh2f(unsigned short h) {
    return __uint_as_float(((unsigned)h) << 16);
}
// split two f32 into packed bf16 hi (rne) and bf16 lo (rne of residual)
__device__ __forceinline__ void split2(float a, float b, unsigned& hi, unsigned& lo) {
    unsigned short ha = rne16(a), hb = rne16(b);
    hi = (unsigned)ha | ((unsigned)hb << 16);
    unsigned short la = rne16(a - bfh2f(ha)), lb = rne16(b - bfh2f(hb));
    lo = (unsigned)la | ((unsigned)lb << 16);
}
// load 8 bf16 from an 8-byte-aligned LDS address as two b64 reads
__device__ __forceinline__ bf16x8 ld_bf16x8_a8(const short* p) {
    s4v a = *(const s4v*)p;
    s4v b = *(const s4v*)(p + 4);
    return __builtin_shufflevector(a, b, 0, 1, 2, 3, 4, 5, 6, 7);
}

__global__ __launch_bounds__(256, 3)
void mha_fused_kernel(const float* __restrict__ x,
                      const float* __restrict__ Wq, const float* __restrict__ bq,
                      const float* __restrict__ Wk, const float* __restrict__ bk,
                      const float* __restrict__ Wv, const float* __restrict__ bv,
                      const float* __restrict__ Wc, const float* __restrict__ bc,
                      float* __restrict__ out)
{
    __shared__ __align__(16) unsigned char smem[SMEM_BYTES];

    const int tid = threadIdx.x;
    const int bth = blockIdx.x;          // [0, 512*6*8)
    const int h   = bth & 7;
    const int bt  = bth >> 3;            // b*T + t

    const int wid  = tid >> 6;           // wave 0..3
    const int lane = tid & 63;
    const int l15  = lane & 15;
    const int quad = lane >> 4;

    // ---------------- Phase 1: q,k,v projections via split-bf16 MFMA ------------------
    f32x4 accs[8];
    #pragma unroll
    for (int jj = 0; jj < 8; ++jj) accs[jj] = (f32x4){0.f, 0.f, 0.f, 0.f};

    for (int chunk = 0; chunk < 4; ++chunk) {    // K = 4 x 64
        __syncthreads();
        {   // x tile: 66 x 64 f32 -> hi/lo bf16
            const float* xg = x + (size_t)bt * S * IN + chunk * 64;
            for (int u = tid; u < 1056; u += 256) {
                int s = u >> 4, c = u & 15;
                float4 v = *(const float4*)(xg + (size_t)s * IN + c * 4);
                uint2 hi, lo;
                split2(v.x, v.y, hi.x, lo.x);
                split2(v.z, v.w, hi.y, lo.y);
                ((uint2*)(smem + XH_OFF + s * 144))[c] = hi;
                ((uint2*)(smem + XL_OFF + s * 144))[c] = lo;
            }
        }
        for (int u = tid; u < 1536; u += 256) {   // W slices: 96 x 64
            int row = u >> 4, c = u & 15;
            int m = row >> 5, dd = row & 31;
            const float* Wm = (m == 0) ? Wq : (m == 1) ? Wk : Wv;
            float4 v = *(const float4*)(Wm + (size_t)(h * 32 + dd) * IN + chunk * 64 + c * 4);
            uint2 hi, lo;
            split2(v.x, v.y, hi.x, lo.x);
            split2(v.z, v.w, hi.y, lo.y);
            ((uint2*)(smem + WH_OFF + row * 144))[c] = hi;
            ((uint2*)(smem + WL_OFF + row * 144))[c] = lo;
        }
        __syncthreads();

        const short* xh = (const short*)(smem + XH_OFF);
        const short* xl = (const short*)(smem + XL_OFF);
        const short* wh = (const short*)(smem + WH_OFF);
        const short* wl = (const short*)(smem + WL_OFF);

        for (int jj = 0; jj < 8; ++jj) {
            int j = wid + 4 * jj;
            if (j >= 30) break;                      // wave-uniform
            int mat = j / 10, rr = j - mat * 10;
            int mtile = rr >> 1, ntile = rr & 1;
            int arow = (mtile * 16 + l15) * 72 + quad * 8;
            int brow = (mat * 32 + ntile * 16 + l15) * 72 + quad * 8;
            #pragma unroll
            for (int kk = 0; kk < 2; ++kk) {
                bf16x8 ah = *(const bf16x8*)(xh + arow + kk * 32);
                bf16x8 al = *(const bf16x8*)(xl + arow + kk * 32);
                bf16x8 bh = *(const bf16x8*)(wh + brow + kk * 32);
                bf16x8 bl = *(const bf16x8*)(wl + brow + kk * 32);
                accs[jj] = __builtin_amdgcn_mfma_f32_16x16x32_bf16(ah, bh, accs[jj], 0, 0, 0);
                accs[jj] = __builtin_amdgcn_mfma_f32_16x16x32_bf16(ah, bl, accs[jj], 0, 0, 0);
                accs[jj] = __builtin_amdgcn_mfma_f32_16x16x32_bf16(al, bh, accs[jj], 0, 0, 0);
            }
        }
    }
    __syncthreads();   // stage dead; epilogue overwrites it

    // ---------------- Epilogue: q/k -> hi/lo [s][d]; v -> relu, hi/lo transposed [d][s]
    {
        short* qh = (short*)(smem + QH_OFF); short* ql = (short*)(smem + QL_OFF);
        short* kh = (short*)(smem + KH_OFF); short* kl = (short*)(smem + KL_OFF);
        for (int jj = 0; jj < 8; ++jj) {
            int j = wid + 4 * jj;
            if (j >= 30) break;
            int mat = j / 10, rr = j - mat * 10;
            int mtile = rr >> 1, ntile = rr & 1;
            int dd = ntile * 16 + l15;
            const float* bias_p = (mat == 0) ? bq : (mat == 1) ? bk : bv;
            float bias = bias_p[h * 32 + dd];
            if (mat < 2) {
                short* bh = (mat == 0) ? qh : kh;
                short* bl = (mat == 0) ? ql : kl;
                #pragma unroll
                for (int reg = 0; reg < 4; ++reg) {
                    int s = mtile * 16 + quad * 4 + reg;
                    if (s < 66) {
                        float v = accs[jj][reg] + bias;
                        unsigned short hi = rne16(v);
                        unsigned short lo = rne16(v - bfh2f(hi));
                        bh[s * 36 + dd] = (short)hi;
                        bl[s * 36 + dd] = (short)lo;
                    }
                }
            } else {
                int sbase = mtile * 16 + quad * 4;
                unsigned short hv[4], lv[4];
                #pragma unroll
                for (int reg = 0; reg < 4; ++reg) {
                    int s = sbase + reg;
                    float v = (s < 66) ? fmaxf(accs[jj][reg] + bias, 0.f) : 0.f; // zero K-pad
                    hv[reg] = rne16(v);
                    lv[reg] = rne16(v - bfh2f(hv[reg]));
                }
                uint2 ph, pl;
                ph.x = (unsigned)hv[0] | ((unsigned)hv[1] << 16);
                ph.y = (unsigned)hv[2] | ((unsigned)hv[3] << 16);
                pl.x = (unsigned)lv[0] | ((unsigned)lv[1] << 16);
                pl.y = (unsigned)lv[2] | ((unsigned)lv[3] << 16);
                *(uint2*)(smem + VTH_OFF + dd * 192 + 2 * sbase) = ph;
                *(uint2*)(smem + VTL_OFF + dd * 192 + 2 * sbase) = pl;
            }
        }
        // zero vT cols 80..95 (beyond epilogue coverage; K-pad safety for PV)
        for (int u = tid; u < 512; u += 256) {
            int comp = u >= 256 ? 1 : 0, rem = comp ? u - 256 : u;
            int row = rem >> 3, kcol = 80 + 2 * (rem & 7);
            *(unsigned*)(smem + (comp ? VTL_OFF : VTH_OFF) + row * 192 + 2 * kcol) = 0u;
        }
    }
    __syncthreads();

    // ---------------- Phase 3: sc = mask * (q k^T) / sqrt(D) via split MFMA ----------
    {
        const short* qh = (const short*)(smem + QH_OFF);
        const short* ql = (const short*)(smem + QL_OFF);
        const short* kh = (const short*)(smem + KH_OFF);
        const short* kl = (const short*)(smem + KL_OFF);
        float* sc = (float*)(smem + SC_OFF);
        for (int t = 0; t < 7; ++t) {
            int tt = wid + 4 * t;
            if (tt >= 25) break;                 // wave-uniform
            int mq = tt / 5, mk = tt - mq * 5;
            int aoff = (mq * 16 + l15) * 36 + quad * 8;
            int boff = (mk * 16 + l15) * 36 + quad * 8;
            bf16x8 ah = ld_bf16x8_a8(qh + aoff);
            bf16x8 al = ld_bf16x8_a8(ql + aoff);
            bf16x8 bh = ld_bf16x8_a8(kh + boff);
            bf16x8 bl = ld_bf16x8_a8(kl + boff);
            f32x4 acc = (f32x4){0.f, 0.f, 0.f, 0.f};
            acc = __builtin_amdgcn_mfma_f32_16x16x32_bf16(ah, bh, acc, 0, 0, 0);
            acc = __builtin_amdgcn_mfma_f32_16x16x32_bf16(ah, bl, acc, 0, 0, 0);
            acc = __builtin_amdgcn_mfma_f32_16x16x32_bf16(al, bh, acc, 0, 0, 0);
            int ks = mk * 16 + l15;
            #pragma unroll
            for (int reg = 0; reg < 4; ++reg) {
                int qs = mq * 16 + quad * 4 + reg;
                if (qs < 66 && ks < 66) {
                    bool masked = (qs < J && ks >= 2 * J) || (qs >= 2 * J && ks < J);
                    sc[qs * 66 + ks] = masked ? 0.f : acc[reg] * INV_SQRT_D;
                }
            }
        }
    }
    __syncthreads();

    // ---------------- Phase 4: prune + softmax (16-lane groups, regs + shuffles) ------
    // Writes UNNORMALIZED e as hi/lo bf16 P (1/sum folded into PV); zero K-pad cols.
    {
        const float* sc = (const float*)(smem + SC_OFF);
        const int group = tid >> 4, lane16 = tid & 15;
        float val[5][5];
        #pragma unroll
        for (int i = 0; i < 5; ++i) {
            int r = group + 16 * i;
            #pragma unroll
            for (int tt = 0; tt < 5; ++tt) {
                int c = lane16 + 16 * tt;
                val[i][tt] = (r < 66 && c < 66) ? sc[r * 66 + c] : -INFINITY;
            }
        }
        __syncthreads();   // all sc reads done -> P may overlay sc front

        short* Ph = (short*)(smem + PH_OFF);
        short* Pl = (short*)(smem + PL_OFF);
        float* inv = (float*)(smem + INV_OFF);
        #pragma unroll
        for (int i = 0; i < 5; ++i) {
            int r = group + 16 * i;
            if (r >= 66) continue;               // group-uniform
            float m = -INFINITY;
            #pragma unroll
            for (int tt = 0; tt < 5; ++tt) m = fmaxf(m, val[i][tt]);
            m = fmaxf(m, __shfl_xor(m, 1));
            m = fmaxf(m, __shfl_xor(m, 2));
            m = fmaxf(m, __shfl_xor(m, 4));
            m = fmaxf(m, __shfl_xor(m, 8));
            const float thr = m / 9.0f;
            float e[5], lsum = 0.f, rmax = -INFINITY;
            #pragma unroll
            for (int tt = 0; tt < 5; ++tt) {
                float sv = val[i][tt];
                float pr = (fabsf(sv) <= thr) ? NEG : sv;   // -INF sentinels stay below
                val[i][tt] = pr;
                rmax = fmaxf(rmax, pr);
            }
            rmax = fmaxf(rmax, __shfl_xor(rmax, 1));
            rmax = fmaxf(rmax, __shfl_xor(rmax, 2));
            rmax = fmaxf(rmax, __shfl_xor(rmax, 4));
            rmax = fmaxf(rmax, __shfl_xor(rmax, 8));
            #pragma unroll
            for (int tt = 0; tt < 5; ++tt) {
                int c = lane16 + 16 * tt;
                float ev = (c < 66) ? __expf(val[i][tt] - rmax) : 0.f;
                e[tt] = ev;
                lsum += ev;
            }
            lsum += __shfl_xor(lsum, 1);
            lsum += __shfl_xor(lsum, 2);
            lsum += __shfl_xor(lsum, 4);
            lsum += __shfl_xor(lsum, 8);
            #pragma unroll
            for (int tt = 0; tt < 6; ++tt) {     // cols 0..95: data or zero pad
                int c = lane16 + 16 * tt;
                if (c >= 104) continue;
                unsigned short hi = 0, lo = 0;
                if (c < 66) {
                    float ev = e[tt];
                    hi = rne16(ev);
                    lo = rne16(ev - bfh2f(hi));
                }
                if (c < 96) {
                    Ph[r * 104 + c] = (short)hi;
                    Pl[r * 104 + c] = (short)lo;
                }
            }
            if (lane16 == 0) inv[r] = 1.0f / lsum;
        }
    }
    __syncthreads();

    // ---------------- Phase 5: aoT = (P @ v)^T * inv, bf16-hi, via MFMA --------------
    {
        const short* Ph = (const short*)(smem + PH_OFF);
        const short* Pl = (const short*)(smem + PL_OFF);
        const short* vh = (const short*)(smem + VTH_OFF);
        const short* vl = (const short*)(smem + VTL_OFF);
        const float* inv = (const float*)(smem + INV_OFF);
        for (int t = 0; t < 3; ++t) {
            int tt = wid + 4 * t;
            if (tt >= 10) break;
            int mq = tt >> 1, nd = tt & 1;
            f32x4 acc = (f32x4){0.f, 0.f, 0.f, 0.f};
            #pragma unroll
            for (int ks = 0; ks < 3; ++ks) {
                const short* ap  = Ph + (mq * 16 + l15) * 104 + ks * 32 + quad * 8;
                const short* alp = Pl + (mq * 16 + l15) * 104 + ks * 32 + quad * 8;
                const short* bp  = vh + (nd * 16 + l15) * 96 + ks * 32 + quad * 8;
                const short* blp = vl + (nd * 16 + l15) * 96 + ks * 32 + quad * 8;
                bf16x8 a   = *(const bf16x8*)ap;
                bf16x8 al8 = *(const bf16x8*)alp;
                bf16x8 b   = *(const bf16x8*)bp;
                bf16x8 bl8 = *(const bf16x8*)blp;
                acc = __builtin_amdgcn_mfma_f32_16x16x32_bf16(a, b, acc, 0, 0, 0);
                acc = __builtin_amdgcn_mfma_f32_16x16x32_bf16(al8, b, acc, 0, 0, 0);
                acc = __builtin_amdgcn_mfma_f32_16x16x32_bf16(a, bl8, acc, 0, 0, 0);
            }
            int dd = nd * 16 + l15, sbase = mq * 16 + quad * 4;
            unsigned short hv[4];
            #pragma unroll
            for (int reg = 0; reg < 4; ++reg) {
                int qs = sbase + reg;
                float o = (qs < 66) ? acc[reg] * inv[qs] : 0.f;   // zero K-pad
                hv[reg] = rne16(o);
            }
            uint2 pk;
            pk.x = (unsigned)hv[0] | ((unsigned)hv[1] << 16);
            pk.y = (unsigned)hv[2] | ((unsigned)hv[3] << 16);
            *(uint2*)(smem + AOT_OFF + dd * 208 + 2 * sbase) = pk;
        }
        // zero aoT cols 80..103
        for (int u = tid; u < 384; u += 256) {
            int row = u / 12, kcol = 80 + 2 * (u % 12);
            *(unsigned*)(smem + AOT_OFF + row * 208 + 2 * kcol) = 0u;
        }
    }
    __syncthreads();

    // ---------------- Stage Wc hi/lo (overlays dead sc/vT) ---------------------------
    {
        for (int u = tid; u < 726; u += 256) {           // 22 rows x 33 float2
            int row = u / 33, cp = u - row * 33;
            float2 w = *(const float2*)(Wc + row * 66 + 2 * cp);
            unsigned hi, lo;
            split2(w.x, w.y, hi, lo);
            *(unsigned*)(smem + WCH_OFF + row * 208 + 4 * cp) = hi;
            *(unsigned*)(smem + WCL_OFF + row * 208 + 4 * cp) = lo;
        }
        for (int u = tid; u < 836; u += 256) {           // zero cols 66..103, rows 0..21
            int comp = u >= 418 ? 1 : 0, rem = comp ? u - 418 : u;
            int row = rem / 19, kcol = 66 + 2 * (rem % 19);
            *(unsigned*)(smem + (comp ? WCL_OFF : WCH_OFF) + row * 208 + 2 * kcol) = 0u;
        }
    }
    __syncthreads();

    // ---------------- Phase 6: out = Wc @ ao + bc via MFMA ---------------------------
    {
        const short* Wch = (const short*)(smem + WCH_OFF);
        const short* Wcl = (const short*)(smem + WCL_OFF);
        const short* aoT = (const short*)(smem + AOT_OFF);
        int mj = wid >> 1, nd = wid & 1;
        f32x4 acc = (f32x4){0.f, 0.f, 0.f, 0.f};
        #pragma unroll
        for (int ks = 0; ks < 3; ++ks) {
            bf16x8 a   = *(const bf16x8*)(Wch + (mj * 16 + l15) * 104 + ks * 32 + quad * 8);
            bf16x8 al8 = *(const bf16x8*)(Wcl + (mj * 16 + l15) * 104 + ks * 32 + quad * 8);
            bf16x8 b   = *(const bf16x8*)(aoT + (nd * 16 + l15) * 104 + ks * 32 + quad * 8);
            acc = __builtin_amdgcn_mfma_f32_16x16x32_bf16(a, b, acc, 0, 0, 0);
            acc = __builtin_amdgcn_mfma_f32_16x16x32_bf16(al8, b, acc, 0, 0, 0);
        }
        int dd = nd * 16 + l15;
        #pragma unroll
        for (int reg = 0; reg < 4; ++reg) {
            int j = mj * 16 + quad * 4 + reg;
            if (j < 22) {
                size_t o = (size_t)(bt * J + j) * (H * D) + h * 32 + dd;
                out[o] = acc[reg] + bc[j];
            }
        }
    }
}

extern "C" void kernel_launch(void* const* d_in, const int* in_sizes, int n_in,
                              void* d_out, int out_size, void* d_ws, size_t ws_size,
                              hipStream_t stream) {
    const float* x  = (const float*)d_in[0];
    const float* Wq = (const float*)d_in[1];
    const float* bq = (const float*)d_in[2];
    const float* Wk = (const float*)d_in[3];
    const float* bk = (const float*)d_in[4];
    const float* Wv = (const float*)d_in[5];
    const float* bv = (const float*)d_in[6];
    const float* Wc = (const float*)d_in[7];
    const float* bc = (const float*)d_in[8];
    float* out = (float*)d_out;

    const int B = 512;
    dim3 grid(B * T * H), block(256);
    hipLaunchKernelGGL(mha_fused_kernel, grid, block, 0, stream,
                       x, Wq, bq, Wk, bk, Wv, bv, Wc, bc, out);
}